// Round 12
// baseline (209.766 us; speedup 1.0000x reference)
//
#include <hip/hip_runtime.h>

using i32x4 = __attribute__((ext_vector_type(4))) int;

#define DEVI static __device__ __forceinline__

DEVI void gload_lds16(const void* g, void* l) {
  __builtin_amdgcn_global_load_lds(
      (const __attribute__((address_space(1))) void*)g,
      (__attribute__((address_space(3))) void*)l, 16, 0, 0);
}

template <int N> DEVI void vmcnt_n() {
  asm volatile("s_waitcnt vmcnt(%0)" ::"n"(N) : "memory");
}

#define FENCE() asm volatile("" ::: "memory")
#define BARX()                    \
  do {                            \
    FENCE();                      \
    __builtin_amdgcn_s_barrier(); \
    FENCE();                      \
  } while (0)
#define PRIO1() __builtin_amdgcn_s_setprio(1)
#define PRIO0() __builtin_amdgcn_s_setprio(0)

// ---------------- fused pre-pass: pack W0/W2/W4 + quantize x ----------------
__global__ void __launch_bounds__(256) prep_kernel(
    const int* __restrict__ W0, const int* __restrict__ W2,
    const int* __restrict__ W4, const float* __restrict__ x,
    const float* __restrict__ amax, signed char* __restrict__ W0q,
    signed char* __restrict__ W2q, signed char* __restrict__ W4q,
    signed char* __restrict__ xq, int c0, int c2, int c4, int cx) {
  const float s = 127.0f / amax[0];
  const int cw = c0 + c2 + c4;
  const int total = cw + cx;
  int stride = gridDim.x * blockDim.x;
  for (int i = blockIdx.x * blockDim.x + threadIdx.x; i < total; i += stride) {
    if (i < cw) {
      const int* w;
      signed char* o;
      int j = i;
      if (j < c0) {
        w = W0; o = W0q;
      } else if (j < c0 + c2) {
        j -= c0; w = W2; o = W2q;
      } else {
        j -= c0 + c2; w = W4; o = W4q;
      }
      int4 v = reinterpret_cast<const int4*>(w)[j];
      char4 c;
      c.x = (signed char)v.x;
      c.y = (signed char)v.y;
      c.z = (signed char)v.z;
      c.w = (signed char)v.w;
      reinterpret_cast<char4*>(o)[j] = c;
    } else {
      int j = i - cw;
      float4 v = reinterpret_cast<const float4*>(x)[j];
      char4 c;
      float q;
      q = fminf(fmaxf(rintf(__fmul_rn(v.x, s)), -127.0f), 127.0f); c.x = (signed char)(int)q;
      q = fminf(fmaxf(rintf(__fmul_rn(v.y, s)), -127.0f), 127.0f); c.y = (signed char)(int)q;
      q = fminf(fmaxf(rintf(__fmul_rn(v.z, s)), -127.0f), 127.0f); c.z = (signed char)(int)q;
      q = fminf(fmaxf(rintf(__fmul_rn(v.w, s)), -127.0f), 127.0f); c.w = (signed char)(int)q;
      reinterpret_cast<char4*>(xq)[j] = c;
    }
  }
}

// ---- int8 GEMM: triple-buffered LDS (BK=64), fully decoupled pipeline ----
// A: [M,K] i8 row-major; W: [N,K] i8 row-major. BM=256.
// Tile t: MFMA consumes regs loaded during t-1 (zero LDS waits); issues
// prefetch reads of tile t+1 (no consumer this tile) + stage DMA of tile
// t+2; vmcnt(0) (1-tile cover) + barrier. Buf X: staged t-1, drained end
// t-1, published barrier, read t, consumed t+1, restaged t+2. All waits
// own-wave, same-class. Swizzle = R11's (measured 0 conflicts).

#define STG(bofs, kt)                                                          \
  do {                                                                         \
    const int k0_ = (kt)*64 + scol;                                            \
    gload_lds16(Ab + (size_t)(srow)*K + k0_, lp + (bofs) + tid * 16);          \
    gload_lds16(Ab + (size_t)(128 + srow) * K + k0_,                           \
                lp + (bofs) + 8192 + tid * 16);                                \
    gload_lds16(Wb + (size_t)(srow)*K + k0_, lp + (bofs) + ASZ + tid * 16);    \
    if constexpr (BN == 256)                                                   \
      gload_lds16(Wb + (size_t)(128 + srow) * K + k0_,                         \
                  lp + (bofs) + ASZ + 8192 + tid * 16);                        \
  } while (0)

#define PREFETCH(afN, bfN)                                                   \
  do {                                                                       \
    _Pragma("unroll") for (int m = 0; m < MF; ++m) afN[m] =                  \
        *(const i32x4*)&lp[nxt + (wrl + m * 16 + ro) * 64 + cS];             \
    _Pragma("unroll") for (int n = 0; n < NN; ++n) bfN[n] =                  \
        *(const i32x4*)&lp[nxt + ASZ + (wcl + n * 16 + ro) * 64 + cS];       \
  } while (0)

#define TILE(t, afC, bfC, afN, bfN)                                     \
  do {                                                                  \
    if ((t) + 1 < nt) PREFETCH(afN, bfN);                               \
    if ((t) + 2 < nt) STG(stg, (t) + 2);                                \
    PRIO1();                                                            \
    _Pragma("unroll") for (int m = 0; m < MF; ++m)                      \
        _Pragma("unroll") for (int n = 0; n < NN; ++n) acc[m][n] =      \
            __builtin_amdgcn_mfma_i32_16x16x64_i8(afC[m], bfC[n],       \
                                                  acc[m][n], 0, 0, 0);  \
    PRIO0();                                                            \
    vmcnt_n<0>();                                                       \
    BARX();                                                             \
    { const int tmp_ = cur; cur = nxt; nxt = stg; stg = tmp_; }         \
  } while (0)

template <int BN, int MW, int OUT_I8>
__global__ __launch_bounds__(512, 2) void gemm_r12_kernel(
    const signed char* __restrict__ A, const signed char* __restrict__ W,
    const int* __restrict__ bias, void* __restrict__ out, int M, int N, int K,
    const float* __restrict__ p_ain, const float* __restrict__ p_aw,
    const float* __restrict__ p_ab, const float* __restrict__ p_anext) {
  constexpr int NW = 8 / MW;
  constexpr int MF = 256 / MW / 16;  // m-frags per wave
  constexpr int NN = BN / NW / 16;   // n-frags per wave
  constexpr int ASZ = 256 * 64;      // 16 KiB A per buffer
  constexpr int BSZ = BN * 64;
  constexpr int BUFSZ = ASZ + BSZ;
  __shared__ signed char lds[3 * BUFSZ];
  signed char* lp = lds;

  const int tid = threadIdx.x;
  const int lane = tid & 63;
  const int wave = tid >> 6;
  const int wrl = (wave / NW) * (256 / MW);
  const int wcl = (wave % NW) * (BN / NW);

  // bijective XCD-chunked swizzle (nwg = 256, multiple of 8)
  const int lin = blockIdx.y * gridDim.x + blockIdx.x;
  const int cpx = (gridDim.x * gridDim.y) >> 3;
  const int swz = (lin & 7) * cpx + (lin >> 3);
  const int tileM = (swz / gridDim.x) * 256;
  const int tileN = (swz % gridDim.x) * BN;

  const signed char* Ab = A + (size_t)tileM * K;
  const signed char* Wb = W + (size_t)tileN * K;

  const int srow = tid >> 2;                              // staging row 0..127
  const int scol = ((tid & 3) ^ ((srow >> 1) & 3)) * 16;  // inverse-swz src col

  const int ro = lane & 15;  // fragment row within 16
  const int kg = lane >> 4;  // 16B k-group 0..3
  const int cS = ((kg ^ ((ro >> 1) & 3)) << 4);  // swizzled slot (R11-verified)

  const int nt = K >> 6;  // K-tiles of 64 bytes (even for all layers)

  i32x4 acc[MF][NN] = {};
  i32x4 afA[MF], bfA[NN], afB[MF], bfB[NN];

  int cur = 0, nxt = BUFSZ, stg = 2 * BUFSZ;

  // prologue: stage tiles 0,1; drain; publish; load tile-0 regs from buf0
  STG(0, 0);
  STG(BUFSZ, 1);
  vmcnt_n<0>();
  BARX();
#pragma unroll
  for (int m = 0; m < MF; ++m)
    afA[m] = *(const i32x4*)&lp[cur + (wrl + m * 16 + ro) * 64 + cS];
#pragma unroll
  for (int n = 0; n < NN; ++n)
    bfA[n] = *(const i32x4*)&lp[cur + ASZ + (wcl + n * 16 + ro) * 64 + cS];

  for (int t = 0; t < nt; t += 2) {
    TILE(t, afA, bfA, afB, bfB);
    TILE(t + 1, afB, bfB, afA, bfA);
  }

  // ---- epilogue: dequant + bias (+ relu + requant) ----
  const float s1 = __fmul_rn(p_aw[0], p_ain[0]) / 16129.0f;  // a_w*a_in/127^2
  const float s2 = p_ab[0] / 127.0f;                         // a_b/127
  float qs = 0.0f;
  if (OUT_I8) qs = 127.0f / p_anext[0];

#pragma unroll
  for (int m = 0; m < MF; ++m) {
#pragma unroll
    for (int n = 0; n < NN; ++n) {
      const int col = tileN + wcl + n * 16 + ro;
      const int row0 = tileM + wrl + m * 16 + kg * 4;
      const float bv = __fmul_rn((float)bias[col], s2);
#pragma unroll
      for (int i = 0; i < 4; ++i) {
        float y = __fadd_rn(__fmul_rn((float)acc[m][n][i], s1), bv);
        if (OUT_I8) {
          float rl = fmaxf(y, 0.0f);
          float q = fminf(rintf(__fmul_rn(rl, qs)), 127.0f);
          ((signed char*)out)[(size_t)(row0 + i) * N + col] = (signed char)(int)q;
        } else {
          ((float*)out)[(size_t)(row0 + i) * N + col] = y;
        }
      }
    }
  }
}

extern "C" void kernel_launch(void* const* d_in, const int* in_sizes, int n_in,
                              void* d_out, int out_size, void* d_ws, size_t ws_size,
                              hipStream_t stream) {
  const float* x = (const float*)d_in[0];
  const int* W0 = (const int*)d_in[1];
  const int* b0 = (const int*)d_in[2];
  const int* W2 = (const int*)d_in[3];
  const int* b2 = (const int*)d_in[4];
  const int* W4 = (const int*)d_in[5];
  const int* b4 = (const int*)d_in[6];
  const float* a0_in = (const float*)d_in[7];
  const float* a0_w = (const float*)d_in[8];
  const float* a0_b = (const float*)d_in[9];
  const float* a2_in = (const float*)d_in[10];
  const float* a2_w = (const float*)d_in[11];
  const float* a2_b = (const float*)d_in[12];
  const float* a4_in = (const float*)d_in[13];
  const float* a4_w = (const float*)d_in[14];
  const float* a4_b = (const float*)d_in[15];

  constexpr int Bb = 4096, DIN = 2048, H = 4096, DOUT = 2048;
  constexpr size_t MB = 1u << 20;

  char* ws = (char*)d_ws;
  signed char* xq0 = (signed char*)(ws);           //  8 MB  [0,8)
  signed char* xq2 = (signed char*)(ws);           // 16 MB  [0,16) (aliases xq0+W0q, dead then)
  signed char* W0q = (signed char*)(ws + 8 * MB);  //  8 MB  [8,16)
  signed char* W2q = (signed char*)(ws + 16 * MB); // 16 MB  [16,32)
  signed char* W4q = (signed char*)(ws + 32 * MB); //  8 MB  [32,40)
  signed char* xq1 = (signed char*)(ws + 40 * MB); // 16 MB  [40,56)

  prep_kernel<<<2048, 256, 0, stream>>>(W0, W2, W4, x, a0_in, W0q, W2q, W4q,
                                        xq0, H * DIN / 4, H * H / 4,
                                        DOUT * H / 4, Bb * DIN / 4);

  gemm_r12_kernel<256, 2, 1><<<dim3(H / 256, Bb / 256), 512, 0, stream>>>(
      xq0, W0q, b0, xq1, Bb, H, DIN, a0_in, a0_w, a0_b, a2_in);
  gemm_r12_kernel<256, 2, 1><<<dim3(H / 256, Bb / 256), 512, 0, stream>>>(
      xq1, W2q, b2, xq2, Bb, H, H, a2_in, a2_w, a2_b, a4_in);
  gemm_r12_kernel<128, 4, 0><<<dim3(DOUT / 128, Bb / 256), 512, 0, stream>>>(
      xq2, W4q, b4, d_out, Bb, DOUT, H, a4_in, a4_w, a4_b, a4_in);
}

// Round 13
// 166.059 us; speedup vs baseline: 1.2632x; 1.2632x over previous
//
#include <hip/hip_runtime.h>

using i32x4 = __attribute__((ext_vector_type(4))) int;

#define DEVI static __device__ __forceinline__

DEVI void gload_lds16(const void* g, void* l) {
  __builtin_amdgcn_global_load_lds(
      (const __attribute__((address_space(1))) void*)g,
      (__attribute__((address_space(3))) void*)l, 16, 0, 0);
}

template <int N> DEVI void vmcnt_n() {
  asm volatile("s_waitcnt vmcnt(%0)" ::"n"(N) : "memory");
}
template <int N> DEVI void lgkm_n() {
  asm volatile("s_waitcnt lgkmcnt(%0)" ::"n"(N) : "memory");
}

#define FENCE() asm volatile("" ::: "memory")
#define BARX()                    \
  do {                            \
    FENCE();                      \
    __builtin_amdgcn_s_barrier(); \
    FENCE();                      \
  } while (0)
#define SCHB() __builtin_amdgcn_sched_barrier(0)
#define PRIO1() __builtin_amdgcn_s_setprio(1)
#define PRIO0() __builtin_amdgcn_s_setprio(0)

// ------ fused pre-pass: pack W0 int32->int8 + quantize x fp32->int8 ------
__global__ void __launch_bounds__(256) prep_kernel(
    const int* __restrict__ W0, const float* __restrict__ x,
    const float* __restrict__ amax, signed char* __restrict__ W0q,
    signed char* __restrict__ xq, int c0, int cx) {
  const float s = 127.0f / amax[0];
  const int total = c0 + cx;
  int stride = gridDim.x * blockDim.x;
  for (int i = blockIdx.x * blockDim.x + threadIdx.x; i < total; i += stride) {
    if (i < c0) {
      int4 v = reinterpret_cast<const int4*>(W0)[i];
      char4 c;
      c.x = (signed char)v.x;
      c.y = (signed char)v.y;
      c.z = (signed char)v.z;
      c.w = (signed char)v.w;
      reinterpret_cast<char4*>(W0q)[i] = c;
    } else {
      int j = i - c0;
      float4 v = reinterpret_cast<const float4*>(x)[j];
      char4 c;
      float q;
      q = fminf(fmaxf(rintf(__fmul_rn(v.x, s)), -127.0f), 127.0f); c.x = (signed char)(int)q;
      q = fminf(fmaxf(rintf(__fmul_rn(v.y, s)), -127.0f), 127.0f); c.y = (signed char)(int)q;
      q = fminf(fmaxf(rintf(__fmul_rn(v.z, s)), -127.0f), 127.0f); c.z = (signed char)(int)q;
      q = fminf(fmaxf(rintf(__fmul_rn(v.w, s)), -127.0f), 127.0f); c.w = (signed char)(int)q;
      reinterpret_cast<char4*>(xq)[j] = c;
    }
  }
}

// ---- int8 GEMM (R9 structure, unchanged): dbuf swizzled LDS, gload_lds,
// ---- ONE barrier/tile, own-wave lgkm ledger, vmcnt(0) tile-end drain.
// ---- NEW: optional post-epilogue grid-stride pack tail (next layer's W)
// ---- so weight packing overlaps the GEMM via block stagger + idle HBM.
// A: [M,K] i8 row-major; W: [N,K] i8 row-major. BM=256, BK=128 bytes.
// 8 waves (2M x 4N), per-wave C = 128 x (BN/4).

#define STG(b, kt)                                                               \
  do {                                                                           \
    const int k0_ = (kt)*128 + scol;                                             \
    _Pragma("unroll") for (int j = 0; j < NN; ++j)                               \
        gload_lds16(Wb + (size_t)((j)*64 + srow) * K + k0_,                      \
                    &lds[b][ABYTES + (j)*8192 + tid * 16]);                      \
    gload_lds16(Ab + (size_t)(srow) * K + k0_, &lds[b][tid * 16]);               \
    gload_lds16(Ab + (size_t)(64 + srow) * K + k0_, &lds[b][8192 + tid * 16]);   \
    gload_lds16(Ab + (size_t)(128 + srow) * K + k0_, &lds[b][16384 + tid * 16]); \
    gload_lds16(Ab + (size_t)(192 + srow) * K + k0_, &lds[b][24576 + tid * 16]); \
  } while (0)

#define AF_(b, m, h) \
  (*(const i32x4*)&lds[b][(wrl + (m)*16 + ro) * 128 + ((h) ? cS1 : cS0)])
#define BF_(b, n, h) \
  (*(const i32x4*)&lds[b][ABYTES + (wcl + (n)*16 + ro) * 128 + ((h) ? cS1 : cS0)])

#define RD_AF(dst, b, m0)            \
  do {                               \
    dst[0][0] = AF_(b, m0, 0);       \
    dst[0][1] = AF_(b, m0, 1);       \
    dst[1][0] = AF_(b, (m0) + 1, 0); \
    dst[1][1] = AF_(b, (m0) + 1, 1); \
  } while (0)

#define READ_BF(b)                                   \
  do {                                               \
    _Pragma("unroll") for (int n = 0; n < NN; ++n) { \
      bf[n][0] = BF_(b, n, 0);                       \
      bf[n][1] = BF_(b, n, 1);                       \
    }                                                \
  } while (0)

#define MFMA_P(mp, af)                                                                     \
  do {                                                                                     \
    _Pragma("unroll") for (int n = 0; n < NN; ++n) {                                       \
      acc[2 * (mp)][n] =                                                                   \
          __builtin_amdgcn_mfma_i32_16x16x64_i8(af[0][0], bf[n][0], acc[2 * (mp)][n], 0, 0, 0); \
      acc[2 * (mp)][n] =                                                                   \
          __builtin_amdgcn_mfma_i32_16x16x64_i8(af[0][1], bf[n][1], acc[2 * (mp)][n], 0, 0, 0); \
      acc[2 * (mp) + 1][n] = __builtin_amdgcn_mfma_i32_16x16x64_i8(                        \
          af[1][0], bf[n][0], acc[2 * (mp) + 1][n], 0, 0, 0);                              \
      acc[2 * (mp) + 1][n] = __builtin_amdgcn_mfma_i32_16x16x64_i8(                        \
          af[1][1], bf[n][1], acc[2 * (mp) + 1][n], 0, 0, 0);                              \
    }                                                                                      \
  } while (0)

// lgkm ledger (own-wave ds_reads only):
//  issue afX(4)+BF(8)+afY(4)=16; lgkm(4) retires afX+BF -> MFMA0(afX)
//  issue afX'(4); lgkm(4) retires afY -> MFMA1(afY); issue afY'(4);
//  lgkm(4) retires afX' -> MFMA2; lgkm(0) -> MFMA3.
#define TILE_1B(b, t)                              \
  do {                                             \
    RD_AF(afX, b, 0);                              \
    READ_BF(b);                                    \
    RD_AF(afY, b, 2);                              \
    if ((t) + 1 < nt) STG(1 - (b), (t) + 1);       \
    lgkm_n<4>(); SCHB();                           \
    PRIO1(); MFMA_P(0, afX); PRIO0();              \
    RD_AF(afX, b, 4);                              \
    lgkm_n<4>(); SCHB();                           \
    PRIO1(); MFMA_P(1, afY); PRIO0();              \
    RD_AF(afY, b, 6);                              \
    lgkm_n<4>(); SCHB();                           \
    PRIO1(); MFMA_P(2, afX); PRIO0();              \
    lgkm_n<0>(); SCHB();                           \
    PRIO1(); MFMA_P(3, afY); PRIO0();              \
    vmcnt_n<0>();                                  \
  } while (0)

template <int BN, int OUT_I8>
__global__ __launch_bounds__(512, 2) void gemm_r13_kernel(
    const signed char* __restrict__ A, const signed char* __restrict__ W,
    const int* __restrict__ bias, void* __restrict__ out, int M, int N, int K,
    const float* __restrict__ p_ain, const float* __restrict__ p_aw,
    const float* __restrict__ p_ab, const float* __restrict__ p_anext,
    const int* __restrict__ pw, signed char* __restrict__ po, int pn4) {
  static_assert(BN == 256 || BN == 128, "");
  constexpr int NN = BN / 64;
  constexpr int ABYTES = 256 * 128;  // 32 KiB A-tile
  __shared__ signed char lds[2][ABYTES + BN * 128];

  const int tid = threadIdx.x;
  const int lane = tid & 63;
  const int wave = tid >> 6;
  const int wrl = (wave >> 2) * 128;      // wave row offset in 256
  const int wcl = (wave & 3) * (BN / 4);  // wave col offset in BN

  // bijective XCD-chunked swizzle (nwg multiple of 8)
  const int lin = blockIdx.y * gridDim.x + blockIdx.x;
  const int cpx = (gridDim.x * gridDim.y) >> 3;
  const int swz = (lin & 7) * cpx + (lin >> 3);
  const int tileM = (swz / gridDim.x) * 256;
  const int tileN = (swz % gridDim.x) * BN;

  const signed char* Ab = A + (size_t)tileM * K;
  const signed char* Wb = W + (size_t)tileN * K;

  const int srow = tid >> 3;                       // staging row 0..63
  const int scol = ((tid & 7) ^ (srow & 7)) * 16;  // inverse-swizzled src col

  const int ro = lane & 15;  // fragment row within 16
  const int kg = lane >> 4;  // 16B k-group 0..3
  const int cS0 = ((kg ^ (ro & 7)) << 4);        // swizzled slot, k-half 0
  const int cS1 = (((4 + kg) ^ (ro & 7)) << 4);  // swizzled slot, k-half 1

  const int nt = K >> 7;  // K-tiles of 128 bytes

  i32x4 acc[8][NN] = {};
  i32x4 afX[2][2], afY[2][2], bf[NN][2];

  // prologue: stage tile 0, retire own issues; loop-entry barrier publishes
  STG(0, 0);
  vmcnt_n<0>();

  for (int t = 0; t < nt; t += 2) {
    BARX();
    TILE_1B(0, t);
    BARX();
    TILE_1B(1, t + 1);
  }

  // ---- epilogue: dequant + bias (+ relu + requant) ----
  const float s1 = __fmul_rn(p_aw[0], p_ain[0]) / 16129.0f;  // a_w*a_in/127^2
  const float s2 = p_ab[0] / 127.0f;                         // a_b/127
  float qs = 0.0f;
  if (OUT_I8) qs = 127.0f / p_anext[0];

#pragma unroll
  for (int m = 0; m < 8; ++m) {
#pragma unroll
    for (int n = 0; n < NN; ++n) {
      const int col = tileN + wcl + n * 16 + ro;
      const int row0 = tileM + wrl + m * 16 + kg * 4;
      const float bv = __fmul_rn((float)bias[col], s2);
#pragma unroll
      for (int i = 0; i < 4; ++i) {
        float y = __fadd_rn(__fmul_rn((float)acc[m][n][i], s1), bv);
        if (OUT_I8) {
          float rl = fmaxf(y, 0.0f);
          float q = fminf(rintf(__fmul_rn(rl, qs)), 127.0f);
          ((signed char*)out)[(size_t)(row0 + i) * N + col] = (signed char)(int)q;
        } else {
          ((float*)out)[(size_t)(row0 + i) * N + col] = y;
        }
      }
    }
  }

  // ---- pack tail: next layer's weights, overlapped via block stagger ----
  if (pw != nullptr) {
    const int nblk = gridDim.x * gridDim.y;
    const int stride = nblk * 512;
    for (int i = lin * 512 + tid; i < pn4; i += stride) {
      int4 v = reinterpret_cast<const int4*>(pw)[i];
      char4 c;
      c.x = (signed char)v.x;
      c.y = (signed char)v.y;
      c.z = (signed char)v.z;
      c.w = (signed char)v.w;
      reinterpret_cast<char4*>(po)[i] = c;
    }
  }
}

extern "C" void kernel_launch(void* const* d_in, const int* in_sizes, int n_in,
                              void* d_out, int out_size, void* d_ws, size_t ws_size,
                              hipStream_t stream) {
  const float* x = (const float*)d_in[0];
  const int* W0 = (const int*)d_in[1];
  const int* b0 = (const int*)d_in[2];
  const int* W2 = (const int*)d_in[3];
  const int* b2 = (const int*)d_in[4];
  const int* W4 = (const int*)d_in[5];
  const int* b4 = (const int*)d_in[6];
  const float* a0_in = (const float*)d_in[7];
  const float* a0_w = (const float*)d_in[8];
  const float* a0_b = (const float*)d_in[9];
  const float* a2_in = (const float*)d_in[10];
  const float* a2_w = (const float*)d_in[11];
  const float* a2_b = (const float*)d_in[12];
  const float* a4_in = (const float*)d_in[13];
  const float* a4_w = (const float*)d_in[14];
  const float* a4_b = (const float*)d_in[15];

  constexpr int Bb = 4096, DIN = 2048, H = 4096, DOUT = 2048;
  constexpr size_t MB = 1u << 20;

  char* ws = (char*)d_ws;
  signed char* xq0 = (signed char*)(ws);           //  8 MB  [0,8)
  signed char* xq2 = (signed char*)(ws);           // 16 MB  [0,16) (aliases xq0+W0q, dead then)
  signed char* W0q = (signed char*)(ws + 8 * MB);  //  8 MB  [8,16)
  signed char* W2q = (signed char*)(ws + 16 * MB); // 16 MB  [16,32)
  signed char* W4q = (signed char*)(ws + 32 * MB); //  8 MB  [32,40)
  signed char* xq1 = (signed char*)(ws + 40 * MB); // 16 MB  [40,56)

  // prepass: only what GEMM1 needs (W0 pack + x quant)
  prep_kernel<<<2048, 256, 0, stream>>>(W0, x, a0_in, W0q, xq0, H * DIN / 4,
                                        Bb * DIN / 4);

  // GEMM1 packs W2 in its tail; GEMM2 packs W4; GEMM3 packs nothing.
  gemm_r13_kernel<256, 1><<<dim3(H / 256, Bb / 256), 512, 0, stream>>>(
      xq0, W0q, b0, xq1, Bb, H, DIN, a0_in, a0_w, a0_b, a2_in,
      W2, W2q, H * H / 4);
  gemm_r13_kernel<256, 1><<<dim3(H / 256, Bb / 256), 512, 0, stream>>>(
      xq1, W2q, b2, xq2, Bb, H, H, a2_in, a2_w, a2_b, a4_in,
      W4, W4q, DOUT * H / 4);
  gemm_r13_kernel<128, 0><<<dim3(DOUT / 128, Bb / 256), 512, 0, stream>>>(
      xq2, W4q, b4, d_out, Bb, DOUT, H, a4_in, a4_w, a4_b, a4_in,
      nullptr, nullptr, 0);
}

// Round 14
// 158.616 us; speedup vs baseline: 1.3225x; 1.0469x over previous
//
#include <hip/hip_runtime.h>

using i32x4 = __attribute__((ext_vector_type(4))) int;

#define DEVI static __device__ __forceinline__

DEVI void gload_lds16(const void* g, void* l) {
  __builtin_amdgcn_global_load_lds(
      (const __attribute__((address_space(1))) void*)g,
      (__attribute__((address_space(3))) void*)l, 16, 0, 0);
}

template <int N> DEVI void vmcnt_n() {
  asm volatile("s_waitcnt vmcnt(%0)" ::"n"(N) : "memory");
}
template <int N> DEVI void lgkm_n() {
  asm volatile("s_waitcnt lgkmcnt(%0)" ::"n"(N) : "memory");
}

#define FENCE() asm volatile("" ::: "memory")
#define BARX()                    \
  do {                            \
    FENCE();                      \
    __builtin_amdgcn_s_barrier(); \
    FENCE();                      \
  } while (0)
#define SCHB() __builtin_amdgcn_sched_barrier(0)
#define PRIO1() __builtin_amdgcn_s_setprio(1)
#define PRIO0() __builtin_amdgcn_s_setprio(0)

// ---- fused pre-pass (single launch): pack W0/W2/W4 int32->int8 + quant x ----
__global__ void __launch_bounds__(256) prep_kernel(
    const int* __restrict__ W0, const int* __restrict__ W2,
    const int* __restrict__ W4, const float* __restrict__ x,
    const float* __restrict__ amax, signed char* __restrict__ W0q,
    signed char* __restrict__ W2q, signed char* __restrict__ W4q,
    signed char* __restrict__ xq, int c0, int c2, int c4, int cx) {
  const float s = 127.0f / amax[0];
  const int cw = c0 + c2 + c4;
  const int total = cw + cx;
  int stride = gridDim.x * blockDim.x;
  for (int i = blockIdx.x * blockDim.x + threadIdx.x; i < total; i += stride) {
    if (i < cw) {
      const int* w;
      signed char* o;
      int j = i;
      if (j < c0) {
        w = W0; o = W0q;
      } else if (j < c0 + c2) {
        j -= c0; w = W2; o = W2q;
      } else {
        j -= c0 + c2; w = W4; o = W4q;
      }
      int4 v = reinterpret_cast<const int4*>(w)[j];
      char4 c;
      c.x = (signed char)v.x;
      c.y = (signed char)v.y;
      c.z = (signed char)v.z;
      c.w = (signed char)v.w;
      reinterpret_cast<char4*>(o)[j] = c;
    } else {
      int j = i - cw;
      float4 v = reinterpret_cast<const float4*>(x)[j];
      char4 c;
      float q;
      q = fminf(fmaxf(rintf(__fmul_rn(v.x, s)), -127.0f), 127.0f); c.x = (signed char)(int)q;
      q = fminf(fmaxf(rintf(__fmul_rn(v.y, s)), -127.0f), 127.0f); c.y = (signed char)(int)q;
      q = fminf(fmaxf(rintf(__fmul_rn(v.z, s)), -127.0f), 127.0f); c.z = (signed char)(int)q;
      q = fminf(fmaxf(rintf(__fmul_rn(v.w, s)), -127.0f), 127.0f); c.w = (signed char)(int)q;
      reinterpret_cast<char4*>(xq)[j] = c;
    }
  }
}

// ---- int8 GEMM (R9 structure, verbatim): dbuf swizzled LDS, gload_lds,
// ---- ONE barrier/tile, own-wave lgkm ledger, vmcnt(0) tile-end drain.
// A: [M,K] i8 row-major; W: [N,K] i8 row-major. BM=256, BK=128 bytes.
// 8 waves (2M x 4N), per-wave C = 128 x (BN/4).

#define STG(b, kt)                                                               \
  do {                                                                           \
    const int k0_ = (kt)*128 + scol;                                             \
    _Pragma("unroll") for (int j = 0; j < NN; ++j)                               \
        gload_lds16(Wb + (size_t)((j)*64 + srow) * K + k0_,                      \
                    &lds[b][ABYTES + (j)*8192 + tid * 16]);                      \
    gload_lds16(Ab + (size_t)(srow) * K + k0_, &lds[b][tid * 16]);               \
    gload_lds16(Ab + (size_t)(64 + srow) * K + k0_, &lds[b][8192 + tid * 16]);   \
    gload_lds16(Ab + (size_t)(128 + srow) * K + k0_, &lds[b][16384 + tid * 16]); \
    gload_lds16(Ab + (size_t)(192 + srow) * K + k0_, &lds[b][24576 + tid * 16]); \
  } while (0)

#define AF_(b, m, h) \
  (*(const i32x4*)&lds[b][(wrl + (m)*16 + ro) * 128 + ((h) ? cS1 : cS0)])
#define BF_(b, n, h) \
  (*(const i32x4*)&lds[b][ABYTES + (wcl + (n)*16 + ro) * 128 + ((h) ? cS1 : cS0)])

#define RD_AF(dst, b, m0)            \
  do {                               \
    dst[0][0] = AF_(b, m0, 0);       \
    dst[0][1] = AF_(b, m0, 1);       \
    dst[1][0] = AF_(b, (m0) + 1, 0); \
    dst[1][1] = AF_(b, (m0) + 1, 1); \
  } while (0)

#define READ_BF(b)                                   \
  do {                                               \
    _Pragma("unroll") for (int n = 0; n < NN; ++n) { \
      bf[n][0] = BF_(b, n, 0);                       \
      bf[n][1] = BF_(b, n, 1);                       \
    }                                                \
  } while (0)

#define MFMA_P(mp, af)                                                                     \
  do {                                                                                     \
    _Pragma("unroll") for (int n = 0; n < NN; ++n) {                                       \
      acc[2 * (mp)][n] =                                                                   \
          __builtin_amdgcn_mfma_i32_16x16x64_i8(af[0][0], bf[n][0], acc[2 * (mp)][n], 0, 0, 0); \
      acc[2 * (mp)][n] =                                                                   \
          __builtin_amdgcn_mfma_i32_16x16x64_i8(af[0][1], bf[n][1], acc[2 * (mp)][n], 0, 0, 0); \
      acc[2 * (mp) + 1][n] = __builtin_amdgcn_mfma_i32_16x16x64_i8(                        \
          af[1][0], bf[n][0], acc[2 * (mp) + 1][n], 0, 0, 0);                              \
      acc[2 * (mp) + 1][n] = __builtin_amdgcn_mfma_i32_16x16x64_i8(                        \
          af[1][1], bf[n][1], acc[2 * (mp) + 1][n], 0, 0, 0);                              \
    }                                                                                      \
  } while (0)

// lgkm ledger (own-wave ds_reads only):
//  issue afX(4)+BF(8)+afY(4)=16; lgkm(4) retires afX+BF -> MFMA0(afX)
//  issue afX'(4); lgkm(4) retires afY -> MFMA1(afY); issue afY'(4);
//  lgkm(4) retires afX' -> MFMA2; lgkm(0) -> MFMA3.
#define TILE_1B(b, t)                              \
  do {                                             \
    RD_AF(afX, b, 0);                              \
    READ_BF(b);                                    \
    RD_AF(afY, b, 2);                              \
    if ((t) + 1 < nt) STG(1 - (b), (t) + 1);       \
    lgkm_n<4>(); SCHB();                           \
    PRIO1(); MFMA_P(0, afX); PRIO0();              \
    RD_AF(afX, b, 4);                              \
    lgkm_n<4>(); SCHB();                           \
    PRIO1(); MFMA_P(1, afY); PRIO0();              \
    RD_AF(afY, b, 6);                              \
    lgkm_n<4>(); SCHB();                           \
    PRIO1(); MFMA_P(2, afX); PRIO0();              \
    lgkm_n<0>(); SCHB();                           \
    PRIO1(); MFMA_P(3, afY); PRIO0();              \
    vmcnt_n<0>();                                  \
  } while (0)

template <int BN, int OUT_I8>
__global__ __launch_bounds__(512, 2) void gemm_r14_kernel(
    const signed char* __restrict__ A, const signed char* __restrict__ W,
    const int* __restrict__ bias, void* __restrict__ out, int M, int N, int K,
    const float* __restrict__ p_ain, const float* __restrict__ p_aw,
    const float* __restrict__ p_ab, const float* __restrict__ p_anext) {
  static_assert(BN == 256 || BN == 128, "");
  constexpr int NN = BN / 64;
  constexpr int ABYTES = 256 * 128;  // 32 KiB A-tile
  __shared__ signed char lds[2][ABYTES + BN * 128];

  const int tid = threadIdx.x;
  const int lane = tid & 63;
  const int wave = tid >> 6;
  const int wrl = (wave >> 2) * 128;      // wave row offset in 256
  const int wcl = (wave & 3) * (BN / 4);  // wave col offset in BN

  // bijective XCD-chunked swizzle (nwg multiple of 8)
  const int lin = blockIdx.y * gridDim.x + blockIdx.x;
  const int cpx = (gridDim.x * gridDim.y) >> 3;
  const int swz = (lin & 7) * cpx + (lin >> 3);
  const int tileM = (swz / gridDim.x) * 256;
  const int tileN = (swz % gridDim.x) * BN;

  const signed char* Ab = A + (size_t)tileM * K;
  const signed char* Wb = W + (size_t)tileN * K;

  const int srow = tid >> 3;                       // staging row 0..63
  const int scol = ((tid & 7) ^ (srow & 7)) * 16;  // inverse-swizzled src col

  const int ro = lane & 15;  // fragment row within 16
  const int kg = lane >> 4;  // 16B k-group 0..3
  const int cS0 = ((kg ^ (ro & 7)) << 4);        // swizzled slot, k-half 0
  const int cS1 = (((4 + kg) ^ (ro & 7)) << 4);  // swizzled slot, k-half 1

  const int nt = K >> 7;  // K-tiles of 128 bytes

  i32x4 acc[8][NN] = {};
  i32x4 afX[2][2], afY[2][2], bf[NN][2];

  // prologue: stage tile 0, retire own issues; loop-entry barrier publishes
  STG(0, 0);
  vmcnt_n<0>();

  for (int t = 0; t < nt; t += 2) {
    BARX();
    TILE_1B(0, t);
    BARX();
    TILE_1B(1, t + 1);
  }

  // ---- epilogue: dequant + bias (+ relu + requant) ----
  const float s1 = __fmul_rn(p_aw[0], p_ain[0]) / 16129.0f;  // a_w*a_in/127^2
  const float s2 = p_ab[0] / 127.0f;                         // a_b/127
  float qs = 0.0f;
  if (OUT_I8) qs = 127.0f / p_anext[0];

#pragma unroll
  for (int m = 0; m < 8; ++m) {
#pragma unroll
    for (int n = 0; n < NN; ++n) {
      const int col = tileN + wcl + n * 16 + ro;
      const int row0 = tileM + wrl + m * 16 + kg * 4;
      const float bv = __fmul_rn((float)bias[col], s2);
#pragma unroll
      for (int i = 0; i < 4; ++i) {
        float y = __fadd_rn(__fmul_rn((float)acc[m][n][i], s1), bv);
        if (OUT_I8) {
          float rl = fmaxf(y, 0.0f);
          float q = fminf(rintf(__fmul_rn(rl, qs)), 127.0f);
          ((signed char*)out)[(size_t)(row0 + i) * N + col] = (signed char)(int)q;
        } else {
          ((float*)out)[(size_t)(row0 + i) * N + col] = y;
        }
      }
    }
  }
}

extern "C" void kernel_launch(void* const* d_in, const int* in_sizes, int n_in,
                              void* d_out, int out_size, void* d_ws, size_t ws_size,
                              hipStream_t stream) {
  const float* x = (const float*)d_in[0];
  const int* W0 = (const int*)d_in[1];
  const int* b0 = (const int*)d_in[2];
  const int* W2 = (const int*)d_in[3];
  const int* b2 = (const int*)d_in[4];
  const int* W4 = (const int*)d_in[5];
  const int* b4 = (const int*)d_in[6];
  const float* a0_in = (const float*)d_in[7];
  const float* a0_w = (const float*)d_in[8];
  const float* a0_b = (const float*)d_in[9];
  const float* a2_in = (const float*)d_in[10];
  const float* a2_w = (const float*)d_in[11];
  const float* a2_b = (const float*)d_in[12];
  const float* a4_in = (const float*)d_in[13];
  const float* a4_w = (const float*)d_in[14];
  const float* a4_b = (const float*)d_in[15];

  constexpr int Bb = 4096, DIN = 2048, H = 4096, DOUT = 2048;
  constexpr size_t MB = 1u << 20;

  char* ws = (char*)d_ws;
  signed char* xq0 = (signed char*)(ws);           //  8 MB  [0,8)
  signed char* xq2 = (signed char*)(ws);           // 16 MB  [0,16) (aliases xq0+W0q, dead then)
  signed char* W0q = (signed char*)(ws + 8 * MB);  //  8 MB  [8,16)
  signed char* W2q = (signed char*)(ws + 16 * MB); // 16 MB  [16,32)
  signed char* W4q = (signed char*)(ws + 32 * MB); //  8 MB  [32,40)
  signed char* xq1 = (signed char*)(ws + 40 * MB); // 16 MB  [40,56)

  // single fused pre-pass launch (R12-measured ~20 us vs ~38 for 4 launches)
  prep_kernel<<<2048, 256, 0, stream>>>(W0, W2, W4, x, a0_in, W0q, W2q, W4q,
                                        xq0, H * DIN / 4, H * H / 4,
                                        DOUT * H / 4, Bb * DIN / 4);

  gemm_r14_kernel<256, 1><<<dim3(H / 256, Bb / 256), 512, 0, stream>>>(
      xq0, W0q, b0, xq1, Bb, H, DIN, a0_in, a0_w, a0_b, a2_in);
  gemm_r14_kernel<256, 1><<<dim3(H / 256, Bb / 256), 512, 0, stream>>>(
      xq1, W2q, b2, xq2, Bb, H, H, a2_in, a2_w, a2_b, a4_in);
  gemm_r14_kernel<128, 0><<<dim3(DOUT / 128, Bb / 256), 512, 0, stream>>>(
      xq2, W4q, b4, d_out, Bb, DOUT, H, a4_in, a4_w, a4_b, a4_in);
}